// Round 16
// baseline (80.871 us; speedup 1.0000x reference)
//
#include <hip/hip_runtime.h>
#include <stdint.h>

namespace {
constexpr int kH = 16;
constexpr int kS = 8192;
constexpr int kD = 64;
constexpr int kW = 1024;

typedef __attribute__((ext_vector_type(4)))  float float4_t;
typedef __attribute__((ext_vector_type(4)))  float f32x4;
typedef __attribute__((ext_vector_type(8)))  short bf16x8;
typedef __attribute__((ext_vector_type(8)))  short short8_t;

__device__ __forceinline__ unsigned short f2bf(float f) {
    union { float fv; uint32_t u; } c; c.fv = f;
    return (unsigned short)((c.u + 0x7fffu + ((c.u >> 16) & 1u)) >> 16);
}

__device__ __forceinline__ float fexp2(float x) {
#if __has_builtin(__builtin_amdgcn_exp2f)
    return __builtin_amdgcn_exp2f(x);
#else
    return exp2f(x);
#endif
}

__device__ __forceinline__ void gload16(const void* g, char* l) {
    __builtin_amdgcn_global_load_lds(
        (const __attribute__((address_space(1))) void*)g,
        (__attribute__((address_space(3))) void*)l, 16, 0, 0);
}

// ---- prepass: per 32-key tile, K k-major [g8][r32][8], V^T k-major [g4][d64][8] ----
__global__ __launch_bounds__(256)
void prep_kv(const float* __restrict__ K, const float* __restrict__ V,
             unsigned short* __restrict__ Kb, unsigned short* __restrict__ Vt) {
    __shared__ float tile[64][65];
    const int h   = blockIdx.y;
    const int tix = blockIdx.x;           // 64-seq-row group = 2 key-tiles
    const int s0  = tix * 64;
    const int tid = threadIdx.x;
    const size_t hb = (size_t)h * kS * kD;
    unsigned short* Ko = Kb + hb + (size_t)tix * 4096;
    unsigned short* Vo = Vt + hb + (size_t)tix * 4096;

    // K rows -> LDS
    #pragma unroll
    for (int it = 0; it < 4; ++it) {
        const int n = tid + it * 256;
        const int s = n >> 4, d0 = (n & 15) * 4;
        float4_t v = *(const float4_t*)(K + hb + (size_t)(s0 + s) * kD + d0);
        tile[s][d0 + 0] = v[0]; tile[s][d0 + 1] = v[1];
        tile[s][d0 + 2] = v[2]; tile[s][d0 + 3] = v[3];
    }
    __syncthreads();
    // K out: chunk n = tt*256 + g*32 + rr  <-  K[tt*32+rr][g*8+j]
    #pragma unroll
    for (int i = 0; i < 2; ++i) {
        const int n = tid + i * 256;
        const int tt = n >> 8, g = (n >> 5) & 7, rr = n & 31;
        short8_t o;
        #pragma unroll
        for (int j = 0; j < 8; ++j) o[j] = (short)f2bf(tile[tt * 32 + rr][g * 8 + j]);
        *(short8_t*)(Ko + n * 8) = o;
    }
    __syncthreads();
    // V rows -> LDS
    #pragma unroll
    for (int it = 0; it < 4; ++it) {
        const int n = tid + it * 256;
        const int s = n >> 4, d0 = (n & 15) * 4;
        float4_t v = *(const float4_t*)(V + hb + (size_t)(s0 + s) * kD + d0);
        tile[s][d0 + 0] = v[0]; tile[s][d0 + 1] = v[1];
        tile[s][d0 + 2] = v[2]; tile[s][d0 + 3] = v[3];
    }
    __syncthreads();
    // V out: chunk n = tt*256 + g*64 + d  <-  V[tt*32 + g*8 + j][d]
    #pragma unroll
    for (int i = 0; i < 2; ++i) {
        const int n = tid + i * 256;
        const int tt = n >> 8, g = (n >> 6) & 3, d = n & 63;
        short8_t o;
        #pragma unroll
        for (int j = 0; j < 8; ++j) o[j] = (short)f2bf(tile[tt * 32 + g * 8 + j][d]);
        *(short8_t*)(Vo + n * 8) = o;
    }
}

// ---- main: 16 q/wave (16x16x32 MFMA), KT=32 dbuf 16KB LDS, R6 sync ----
__global__ __launch_bounds__(256, 6)
void swa_main(const float* __restrict__ Qg, const unsigned short* __restrict__ Kb,
              const unsigned short* __restrict__ Vt, float* __restrict__ Og) {
    // per buffer: [0,4K) K tile [g8][r32][8], [4K,8K) V^T tile [g4][d64][8]
    __shared__ __align__(16) char lds[2][8192];

    const int lid  = blockIdx.x;                      // 0..2047
    const int swz  = (lid & 7) * 256 + (lid >> 3);    // XCD-chunked, bijective
    const int h    = swz >> 7;
    const int qblk = swz & 127;

    const int tid  = threadIdx.x;
    const int wv   = tid >> 6;
    const int lane = tid & 63;
    const int lq   = lane & 15;   // q column
    const int a    = lane >> 4;   // row group (0..3)

    const int q0b = qblk * 64;
    const int qs  = q0b + wv * 16;        // wave's 16 queries
    const int qg  = qs + lq;
    const size_t hb = (size_t)h * kS * kD;

    // ---- Q B-frags (2 k-chunks of 32); scale folded with log2(e) ----
    constexpr float qscale = 0.125f * 1.44269504f;
    bf16x8 qf[2];
    {
        const float* qp = Qg + hb + (size_t)qg * kD + a * 8;
        #pragma unroll
        for (int c = 0; c < 2; ++c) {
            float4_t x = *(const float4_t*)(qp + c * 32);
            float4_t y = *(const float4_t*)(qp + c * 32 + 4);
            bf16x8 f;
            #pragma unroll
            for (int j = 0; j < 4; ++j) {
                f[j]     = (short)f2bf(x[j] * qscale);
                f[j + 4] = (short)f2bf(y[j] * qscale);
            }
            qf[c] = f;
        }
    }

    f32x4 acc[4];
    #pragma unroll
    for (int d = 0; d < 4; ++d)
        #pragma unroll
        for (int r = 0; r < 4; ++r) acc[d][r] = 0.f;
    float lp = 0.f;

    const int kstart = (q0b >= kW) ? q0b - kW : 0;
    const int nt     = (q0b + 64 - kstart) >> 5;      // 32-key tiles, >= 2

    const unsigned short* KbH = Kb + hb;
    const unsigned short* VtH = Vt + hb;

    auto stage = [&](int buf, int kb) {
        const unsigned short* Kt = KbH + (size_t)(kb >> 5) * 2048;
        const unsigned short* Vq = VtH + (size_t)(kb >> 5) * 2048;
        const int db = wv * 1024;                     // wave-uniform dest base
        gload16(Kt + tid * 8, &lds[buf][db]);
        gload16(Vq + tid * 8, &lds[buf][4096 + db]);
    };

    const int kbase = lq * 16 + a * 512;              // K A-frag base
    const int vbase = 4096 + lq * 16 + a * 1024;      // V A-frag base
    union U { unsigned int u[4]; bf16x8 v; };

    stage(0, kstart);
    for (int t = 0; t < nt; ++t) {
        const int kb  = kstart + t * 32;
        const int kbn = (t + 1 < nt) ? kb + 32 : kb;
        stage((t + 1) & 1, kbn);                      // prefetch next tile
        asm volatile("s_waitcnt vmcnt(2)" ::: "memory");
        __builtin_amdgcn_s_barrier();
        asm volatile("" ::: "memory");

        const char* B = lds[t & 1];
        const bool active = (kb <= qs + 15) && (kb + 31 >= qs - kW);
        if (active) {
            // K A-frags: [ks][c] at kbase + c*2048 + ks*256
            bf16x8 kf00 = *(const bf16x8*)(B + kbase);
            bf16x8 kf01 = *(const bf16x8*)(B + kbase + 2048);
            bf16x8 kf10 = *(const bf16x8*)(B + kbase + 256);
            bf16x8 kf11 = *(const bf16x8*)(B + kbase + 2304);

            f32x4 st0, st1;
            #pragma unroll
            for (int r = 0; r < 4; ++r) { st0[r] = 0.f; st1[r] = 0.f; }
            __builtin_amdgcn_s_setprio(1);
            st0 = __builtin_amdgcn_mfma_f32_16x16x32_bf16(kf00, qf[0], st0, 0, 0, 0);
            st1 = __builtin_amdgcn_mfma_f32_16x16x32_bf16(kf10, qf[0], st1, 0, 0, 0);
            st0 = __builtin_amdgcn_mfma_f32_16x16x32_bf16(kf01, qf[1], st0, 0, 0, 0);
            st1 = __builtin_amdgcn_mfma_f32_16x16x32_bf16(kf11, qf[1], st1, 0, 0, 0);
            __builtin_amdgcn_s_setprio(0);

            // V A-frags (early issue)
            bf16x8 vf0 = *(const bf16x8*)(B + vbase);
            bf16x8 vf1 = *(const bf16x8*)(B + vbase + 256);
            bf16x8 vf2 = *(const bf16x8*)(B + vbase + 512);
            bf16x8 vf3 = *(const bf16x8*)(B + vbase + 768);

            // ---- max-free softmax numerators ----
            // p[0..3] = keys kb + a*4 + r ; p[4..7] = keys kb+16 + a*4 + r
            float p[8];
            const bool fast = (kb + 31 <= qs) && (kb >= qs + 15 - kW);
            if (fast) {
                #pragma unroll
                for (int r = 0; r < 4; ++r) { p[r] = fexp2(st0[r]); p[4 + r] = fexp2(st1[r]); }
            } else {
                #pragma unroll
                for (int r = 0; r < 4; ++r) {
                    const int k0 = kb + a * 4 + r;
                    const int k1 = k0 + 16;
                    p[r]     = ((k0 <= qg) && (k0 + kW >= qg)) ? fexp2(st0[r]) : 0.f;
                    p[4 + r] = ((k1 <= qg) && (k1 + kW >= qg)) ? fexp2(st1[r]) : 0.f;
                }
            }
            #pragma unroll
            for (int r = 0; r < 8; ++r) lp += p[r];

            // ---- P^T B-frag: lane L (q=L&15, b=L>>4) needs keys 8b..8b+7 ----
            // x0=pk(p0,p1) x1=pk(p2,p3): keys 4a,4a+1 / 4a+2,4a+3 (lo 16)
            // y0=pk(p4,p5) y1=pk(p6,p7): keys 16+4a.. (hi 16)
            // swap(x,y): x={x.lo,y.lo}, y={x.hi,y.hi}; then
            // B0=(b odd)?shfl16(y):x ; B2=(b odd)?y:shfl16(x)  (same for 1/3)
            unsigned int x0, x1, y0, y1;
            asm("v_cvt_pk_bf16_f32 %0, %1, %2" : "=v"(x0) : "v"(p[0]), "v"(p[1]));
            asm("v_cvt_pk_bf16_f32 %0, %1, %2" : "=v"(x1) : "v"(p[2]), "v"(p[3]));
            asm("v_cvt_pk_bf16_f32 %0, %1, %2" : "=v"(y0) : "v"(p[4]), "v"(p[5]));
            asm("v_cvt_pk_bf16_f32 %0, %1, %2" : "=v"(y1) : "v"(p[6]), "v"(p[7]));
            asm("v_permlane32_swap_b32 %0, %1" : "+v"(x0), "+v"(y0));
            asm("v_permlane32_swap_b32 %0, %1" : "+v"(x1), "+v"(y1));
            const unsigned int s0 = (unsigned int)__shfl_xor((int)y0, 16);
            const unsigned int s1 = (unsigned int)__shfl_xor((int)y1, 16);
            const unsigned int t0 = (unsigned int)__shfl_xor((int)x0, 16);
            const unsigned int t1 = (unsigned int)__shfl_xor((int)x1, 16);
            const bool hb16 = (lane & 16) != 0;
            U u;
            u.u[0] = hb16 ? s0 : x0;
            u.u[1] = hb16 ? s1 : x1;
            u.u[2] = hb16 ? y0 : t0;
            u.u[3] = hb16 ? y1 : t1;

            __builtin_amdgcn_s_setprio(1);
            acc[0] = __builtin_amdgcn_mfma_f32_16x16x32_bf16(vf0, u.v, acc[0], 0, 0, 0);
            acc[1] = __builtin_amdgcn_mfma_f32_16x16x32_bf16(vf1, u.v, acc[1], 0, 0, 0);
            acc[2] = __builtin_amdgcn_mfma_f32_16x16x32_bf16(vf2, u.v, acc[2], 0, 0, 0);
            acc[3] = __builtin_amdgcn_mfma_f32_16x16x32_bf16(vf3, u.v, acc[3], 0, 0, 0);
            __builtin_amdgcn_s_setprio(0);
        }

        asm volatile("" ::: "memory");
        __builtin_amdgcn_s_barrier();                 // buf fully read before rewrite
        asm volatile("" ::: "memory");
    }

    // ---- epilogue: l = sum over the 4 row-groups of this q ----
    lp += __shfl_xor(lp, 16);
    lp += __shfl_xor(lp, 32);
    const float rl = 1.f / lp;
    float* op = Og + hb + (size_t)qg * kD;
    #pragma unroll
    for (int d = 0; d < 4; ++d) {
        float4_t o;
        #pragma unroll
        for (int r = 0; r < 4; ++r) o[r] = acc[d][r] * rl;
        *(float4_t*)(op + d * 16 + a * 4) = o;
    }
}
} // namespace

extern "C" void kernel_launch(void* const* d_in, const int* in_sizes, int n_in,
                              void* d_out, int out_size, void* d_ws, size_t ws_size,
                              hipStream_t stream) {
    (void)in_sizes; (void)n_in; (void)out_size; (void)ws_size;
    const float* Q = (const float*)d_in[0];
    const float* K = (const float*)d_in[1];
    const float* V = (const float*)d_in[2];
    float* O = (float*)d_out;
    unsigned short* Kb = (unsigned short*)d_ws;
    unsigned short* Vt = Kb + (size_t)kH * kS * kD;

    prep_kv<<<dim3(kS / 64, kH), dim3(256), 0, stream>>>(K, V, Kb, Vt);
    swa_main<<<dim3(2048), dim3(256), 0, stream>>>(Q, Kb, Vt, O);
}